// Round 1
// baseline (9.588 us; speedup 1.0000x reference)
//
#include <hip/hip_runtime.h>
#include <math.h>

#define N_DENSE   13
#define N_SPARSE  26
#define EMBED_DIM 16
#define VOCAB     100000
#define NB        2048          // batch
#define NCOL      (N_DENSE + N_SPARSE)   // 39

// 32 threads per sample: lane t = tid&31; e = t&15 (embed dim), half = t>>4.
// Each half accumulates 13 features; halves combined via shfl_xor(16).
// pooled[e] = 0.5*(sum^2 - sumsq); out = sigmoid(sum_e pooled[e]*wout[e] + bout).
// (softmax over a size-1 axis is identically 1, so the w1/b1/w2/b2 MLP
//  does not affect the reference output.)
__global__ __launch_bounds__(256) void afm_kernel(
    const int*   __restrict__ inputs,   // (NB, 39) int32
    const float* __restrict__ tables,   // (26, VOCAB, 16) f32
    const float* __restrict__ wout,     // (16,)
    const float* __restrict__ bout,     // (1,)
    float*       __restrict__ out)      // (NB,) f32
{
    int tid = blockIdx.x * blockDim.x + threadIdx.x;
    int b    = tid >> 5;          // sample index
    int t    = tid & 31;          // lane within sample group
    int e    = t & 15;            // embed dim
    int half = t >> 4;            // feature half (0 or 1)
    if (b >= NB) return;

    const int* idx = inputs + b * NCOL + N_DENSE;

    float sum = 0.f, sumsq = 0.f;
    #pragma unroll
    for (int k = 0; k < 13; ++k) {
        int f = half * 13 + k;
        int ix = idx[f];
        float v = tables[((size_t)f * VOCAB + (size_t)ix) * EMBED_DIM + e];
        sum   += v;
        sumsq += v * v;
    }

    // combine the two feature halves (lanes e and e+16 of each 32-group)
    sum   += __shfl_xor(sum,   16, 32);
    sumsq += __shfl_xor(sumsq, 16, 32);

    float pooled  = 0.5f * (sum * sum - sumsq);
    float partial = pooled * wout[e];

    // reduce across the 16 embed lanes (both halves redundantly)
    #pragma unroll
    for (int off = 8; off >= 1; off >>= 1)
        partial += __shfl_xor(partial, off, 16);

    if (t == 0) {
        float s = partial + bout[0];
        out[b] = 1.0f / (1.0f + expf(-s));
    }
}

extern "C" void kernel_launch(void* const* d_in, const int* in_sizes, int n_in,
                              void* d_out, int out_size, void* d_ws, size_t ws_size,
                              hipStream_t stream) {
    const int*   inputs = (const int*)  d_in[0];
    const float* tables = (const float*)d_in[1];
    // d_in[2..5] = w1, b1, w2, b2 — mathematically dead (softmax over size-1 axis == 1)
    const float* wout   = (const float*)d_in[6];
    const float* bout   = (const float*)d_in[7];
    float* out = (float*)d_out;

    const int threads_per_sample = 32;
    const int block = 256;
    const int total = NB * threads_per_sample;      // 65536
    const int grid  = (total + block - 1) / block;  // 256

    afm_kernel<<<grid, block, 0, stream>>>(inputs, tables, wout, bout, out);
}